// Round 9
// baseline (12439.890 us; speedup 1.0000x reference)
//
#include <hip/hip_runtime.h>
#include <hip/hip_bf16.h>
#include <stdint.h>

#define N_NODES 10000
#define N_EDGES 320000
#define N_KEYS  32      // market1/market2 are (32,128) — K=32 in the reference!

// ======================= utility =======================
__global__ void kzero(float* p, long n){
  long i = (long)blockIdx.x*blockDim.x + threadIdx.x;
  long st = (long)gridDim.x*blockDim.x;
  for(; i<n; i+=st) p[i]=0.f;
}

__global__ void izero(int* p, long n){
  long i = (long)blockIdx.x*blockDim.x + threadIdx.x;
  long st = (long)gridDim.x*blockDim.x;
  for(; i<n; i+=st) p[i]=0;
}

__global__ void kprobe(float* out, float v, int n){
  int i = blockIdx.x*256 + threadIdx.x;
  if(i<n) out[i] = (i==0) ? v : 0.f;
}

__global__ void ksum_ew(const float* ew, float* out, int n){
  __shared__ float red[256];
  int gid = blockIdx.x*256 + threadIdx.x;
  red[threadIdx.x] = gid<n ? ew[gid] : 0.f;
  __syncthreads();
  for(int off=128; off>0; off>>=1){
    if(threadIdx.x<off) red[threadIdx.x]+=red[threadIdx.x+off];
    __syncthreads();
  }
  if(threadIdx.x==0) atomicAdd(out, red[0]);
}

// ======================= naive hardened linear =======================
// C(M,N) = A(M,K; lda) * B(N,K; ldb)^T + bias ; one thread per output element.
__global__ void lin_nt(const float* A, int lda, const float* B, int ldb, const float* bias,
    float* C, int ldc, int M, int N, int K, int relu){
  int gid = blockIdx.x*256 + threadIdx.x;
  if(gid >= M*N) return;
  int m = gid / N, n = gid - m*N;
  const float* a = A + (size_t)m*lda;
  const float* b = B + (size_t)n*ldb;
  float s = bias ? bias[n] : 0.f;
  for(int k=0;k<K;k++) s += a[k]*b[k];
  if(relu) s = fmaxf(s, 0.f);
  C[(size_t)m*ldc + n] = s;
}

// ======================= GRU (validated r5) =======================
__global__ __launch_bounds__(256) void gru_attn_logits(const float* h, const float* ga,
    float* L, float* part, int n){
  int row = blockIdx.x*256 + threadIdx.x;
  float acc[5] = {0,0,0,0,0};
  if(row < n){
    const float4* hr = (const float4*)(h + (size_t)row*128);
    for(int k4=0;k4<32;k4++){
      float4 v = hr[k4];
      #pragma unroll
      for(int c=0;c<5;c++){
        const float* g = ga + c*128 + k4*4;
        acc[c] += v.x*g[0]+v.y*g[1]+v.z*g[2]+v.w*g[3];
      }
    }
    #pragma unroll
    for(int c=0;c<5;c++) L[(size_t)row*5+c] = acc[c];
  }
  __shared__ float sm[256], ss[256];
  for(int c=0;c<5;c++){
    sm[threadIdx.x] = row<n ? acc[c] : -3.0e38f;
    ss[threadIdx.x] = row<n ? 1.f : 0.f;
    __syncthreads();
    for(int off=128; off>0; off>>=1){
      if(threadIdx.x < off){
        float m1=sm[threadIdx.x], m2=sm[threadIdx.x+off];
        float s1=ss[threadIdx.x], s2=ss[threadIdx.x+off];
        float M = fmaxf(m1,m2);
        sm[threadIdx.x]=M;
        ss[threadIdx.x]=s1*__expf(m1-M) + s2*__expf(m2-M);
      }
      __syncthreads();
    }
    if(threadIdx.x==0){ part[blockIdx.x*10 + c*2] = sm[0]; part[blockIdx.x*10 + c*2+1] = ss[0]; }
    __syncthreads();
  }
}

__global__ void gru_attn_reduce(const float* part, float* ms, int nblk){
  int c = threadIdx.x;
  if(c>=5) return;
  float M=-3.0e38f, S=0.f;
  for(int b=0;b<nblk;b++){
    float m2=part[b*10+c*2], s2=part[b*10+c*2+1];
    float Mn = fmaxf(M,m2);
    S = S*__expf(M-Mn) + s2*__expf(m2-Mn);
    M = Mn;
  }
  ms[c] = M; ms[5+c] = 1.f/S;
}

__global__ __launch_bounds__(256) void gru_step(const float* h, const float* xts, const float* L,
    const float* ms, const float* wih, const float* whh, float* hout, int t){
  __shared__ float hl[16][128];
  __shared__ float sg[16][256];
  __shared__ float xg[16][5];
  int n0 = blockIdx.x*16;
  int tid = threadIdx.x;
  const float4* src = (const float4*)(h + (size_t)n0*128);
  float4* dst4 = (float4*)&hl[0][0];
  for(int i=tid;i<512;i+=256) dst4[i] = src[i];
  if(tid < 80){
    int i = tid/5, f = tid%5;
    int node = n0+i;
    float xt = xts[(size_t)node*160 + t*5 + f];
    float aw = __expf(L[(size_t)node*5+f] - ms[f]) * ms[5+f];
    xg[i][f] = xt*aw;
  }
  __syncthreads();
  float wf[5];
  #pragma unroll
  for(int f=0;f<5;f++) wf[f] = wih[tid*5+f];
  float acc[16];
  #pragma unroll
  for(int i=0;i<16;i++) acc[i]=0.f;
  const float* wr = whh + (size_t)tid*128;
  for(int k4=0;k4<32;k4++){
    float4 wv = *(const float4*)(wr + k4*4);
    #pragma unroll
    for(int i=0;i<16;i++){
      float4 hv = *(const float4*)&hl[i][k4*4];
      acc[i] += wv.x*hv.x + wv.y*hv.y + wv.z*hv.z + wv.w*hv.w;
    }
  }
  #pragma unroll
  for(int i=0;i<16;i++){
    float g = acc[i];
    #pragma unroll
    for(int f=0;f<5;f++) g += xg[i][f]*wf[f];
    sg[i][tid] = 1.f/(1.f+__expf(-g));
  }
  __syncthreads();
  #pragma unroll
  for(int ii=0;ii<8;ii++){
    int e = tid + ii*256;
    int i = e>>7, col = e&127;
    float r = sg[i][col], u = sg[i][col+128], hv = hl[i][col];
    float nh = u*hv + (1.f-u)*tanhf(r*hv);
    hout[(size_t)(n0+i)*128 + col] = nh;
  }
}

// ======================= tiled fp32 GEMM (validated r5 configs only) =======================
__global__ __launch_bounds__(256) void gemm_abt(const float* A, int lda, const float* B, int ldb,
    const float* bias, float* C, int ldc, int M, int N, int K){
  __shared__ float As[16][68];
  __shared__ float Bs[16][68];
  int m0 = blockIdx.x*64, n0 = blockIdx.y*64;
  int tid = threadIdx.x;
  int tx = tid & 15, ty = tid >> 4;
  float acc[4][4] = {};
  for(int k0=0;k0<K;k0+=16){
    int mm = tid & 63, kc = tid >> 6;
    float4 v = {0,0,0,0};
    if(m0+mm < M) v = *(const float4*)(A + (size_t)(m0+mm)*lda + k0 + kc*4);
    As[kc*4+0][mm]=v.x; As[kc*4+1][mm]=v.y; As[kc*4+2][mm]=v.z; As[kc*4+3][mm]=v.w;
    float4 w = {0,0,0,0};
    if(n0+mm < N) w = *(const float4*)(B + (size_t)(n0+mm)*ldb + k0 + kc*4);
    Bs[kc*4+0][mm]=w.x; Bs[kc*4+1][mm]=w.y; Bs[kc*4+2][mm]=w.z; Bs[kc*4+3][mm]=w.w;
    __syncthreads();
    #pragma unroll
    for(int kk=0;kk<16;kk++){
      float4 a = *(const float4*)&As[kk][ty*4];
      float4 b = *(const float4*)&Bs[kk][tx*4];
      acc[0][0]+=a.x*b.x; acc[0][1]+=a.x*b.y; acc[0][2]+=a.x*b.z; acc[0][3]+=a.x*b.w;
      acc[1][0]+=a.y*b.x; acc[1][1]+=a.y*b.y; acc[1][2]+=a.y*b.z; acc[1][3]+=a.y*b.w;
      acc[2][0]+=a.z*b.x; acc[2][1]+=a.z*b.y; acc[2][2]+=a.z*b.z; acc[2][3]+=a.z*b.w;
      acc[3][0]+=a.w*b.x; acc[3][1]+=a.w*b.y; acc[3][2]+=a.w*b.z; acc[3][3]+=a.w*b.w;
    }
    __syncthreads();
  }
  #pragma unroll
  for(int i=0;i<4;i++){
    #pragma unroll
    for(int j=0;j<4;j++){
      int m = m0+ty*4+i, n = n0+tx*4+j;
      if(m<M && n<N){
        float vv = acc[i][j] + (bias ? bias[n] : 0.f);
        C[(size_t)m*ldc + n] = vv;
      }
    }
  }
}

// ======================= GAT (validated r5) =======================
__global__ void gat_alsd(const float* h, const float* asrc, const float* adst,
    const float* line, const float* aedge, float* al_s, float* al_d, float* ce,
    int n, int heads, int outd){
  int id = blockIdx.x*256 + threadIdx.x;
  if(id < heads){
    float c=0;
    for(int o=0;o<outd;o++) c += line[id*outd+o]*aedge[id*outd+o];
    ce[id]=c;
  }
  if(id >= n*heads) return;
  int node = id/heads, hh = id%heads;
  const float* hr = h + (size_t)node*heads*outd + hh*outd;
  const float* as = asrc + hh*outd;
  const float* ad = adst + hh*outd;
  float s=0.f, d=0.f;
  for(int o=0;o<outd;o++){ float v=hr[o]; s+=v*as[o]; d+=v*ad[o]; }
  al_s[id]=s; al_d[id]=d;
}

__global__ void csr_deg(const int* ei, int* deg, int E, int n){
  int e = blockIdx.x*256+threadIdx.x;
  if(e>=E+n) return;
  int d = e<E ? ei[E+e] : e-E;
  atomicAdd(&deg[d], 1);
}

__global__ void csr_scan(const int* deg, int* rp, int* cur, int n){
  __shared__ int s[1024];
  int carry = 0;
  if(threadIdx.x==0) rp[0]=0;
  for(int c0=0;c0<n;c0+=1024){
    int i = c0+(int)threadIdx.x;
    int v = i<n ? deg[i] : 0;
    s[threadIdx.x]=v;
    __syncthreads();
    for(int off=1; off<1024; off<<=1){
      int t = threadIdx.x>=(unsigned)off ? s[threadIdx.x-off] : 0;
      __syncthreads();
      s[threadIdx.x]+=t;
      __syncthreads();
    }
    if(i<n){ rp[i+1] = carry + s[threadIdx.x]; cur[i] = carry + s[threadIdx.x] - v; }
    carry += s[1023];
    __syncthreads();
  }
}

__global__ void csr_fill(const int* ei, int* cur, int* csr, int E, int n){
  int e = blockIdx.x*256+threadIdx.x;
  if(e>=E+n) return;
  int d = e<E ? ei[E+e] : e-E;
  int slot = atomicAdd(&cur[d], 1);
  csr[slot] = e;
}

__global__ __launch_bounds__(256) void gat_agg(const float* h, const float* al_s, const float* al_d,
    const float* ew, const int* ei, const int* rp, const int* csr, const float* ce, const float* msum,
    const float* bias, float* out, int ldc, int col0, int heads, int outd, int E, int relu){
  int n = blockIdx.x;
  int tid = threadIdx.x;
  int p0 = rp[n], cnt = rp[n+1]-p0;
  float meanw = msum[0] * (1.f/(float)N_EDGES);
  __shared__ float red[256];
  __shared__ float sw[2][256];
  __shared__ int ssrc[256];
  __shared__ float smx[2], sden[2];
  float ald0 = al_d[(size_t)n*heads+0];
  float ald1 = heads>1 ? al_d[(size_t)n*heads+1] : 0.f;
  float ce0 = ce[0], ce1 = heads>1 ? ce[1] : 0.f;
  float mx0=-3.0e38f, mx1=-3.0e38f;
  for(int i=tid;i<cnt;i+=256){
    int e = csr[p0+i];
    int srcn = e<E ? ei[e] : e-E;
    float ea = e<E ? ew[e] : meanw;
    float a0 = al_s[(size_t)srcn*heads+0] + ald0 + ea*ce0;
    a0 = a0>=0.f ? a0 : 0.2f*a0;
    mx0 = fmaxf(mx0,a0);
    if(heads>1){
      float a1 = al_s[(size_t)srcn*heads+1] + ald1 + ea*ce1;
      a1 = a1>=0.f ? a1 : 0.2f*a1;
      mx1 = fmaxf(mx1,a1);
    }
  }
  red[tid]=mx0; __syncthreads();
  for(int off=128;off>0;off>>=1){ if(tid<off) red[tid]=fmaxf(red[tid],red[tid+off]); __syncthreads(); }
  if(tid==0) smx[0]=red[0];
  __syncthreads();
  if(heads>1){
    red[tid]=mx1; __syncthreads();
    for(int off=128;off>0;off>>=1){ if(tid<off) red[tid]=fmaxf(red[tid],red[tid+off]); __syncthreads(); }
    if(tid==0) smx[1]=red[0];
    __syncthreads();
  }
  float den0=0.f, den1=0.f, acc=0.f;
  int myh = outd>0 ? tid/outd : 0;
  int ok = tid < heads*outd;
  if(myh>1) myh=1;
  for(int c0=0;c0<cnt;c0+=256){
    int ccnt = min(256, cnt-c0);
    __syncthreads();
    if(tid < ccnt){
      int e = csr[p0+c0+tid];
      int srcn = e<E ? ei[e] : e-E;
      float ea = e<E ? ew[e] : meanw;
      float a0 = al_s[(size_t)srcn*heads+0] + ald0 + ea*ce0;
      a0 = a0>=0.f ? a0 : 0.2f*a0;
      float w0 = __expf(a0 - smx[0]);
      sw[0][tid]=w0; den0 += w0;
      if(heads>1){
        float a1 = al_s[(size_t)srcn*heads+1] + ald1 + ea*ce1;
        a1 = a1>=0.f ? a1 : 0.2f*a1;
        float w1 = __expf(a1 - smx[1]);
        sw[1][tid]=w1; den1 += w1;
      }
      ssrc[tid]=srcn;
    }
    __syncthreads();
    if(ok){
      for(int j=0;j<ccnt;j++){
        acc += sw[myh][j] * h[(size_t)ssrc[j]*heads*outd + tid];
      }
    }
  }
  red[tid]=den0; __syncthreads();
  for(int off=128;off>0;off>>=1){ if(tid<off) red[tid]+=red[tid+off]; __syncthreads(); }
  if(tid==0) sden[0]=red[0];
  __syncthreads();
  if(heads>1){
    red[tid]=den1; __syncthreads();
    for(int off=128;off>0;off>>=1){ if(tid<off) red[tid]+=red[tid+off]; __syncthreads(); }
    if(tid==0) sden[1]=red[0];
    __syncthreads();
  }
  if(ok){
    float v = acc/(sden[myh]+1e-16f) + bias[tid];
    if(relu) v = fmaxf(v,0.f);
    out[(size_t)n*ldc + col0 + tid] = v;
  }
}

// ======================= attention prep (validated r5) =======================
__global__ void make_wc(const float* wq, const float* wk, const float* bq, float* wct, float* bc){
  int d = blockIdx.x, i = threadIdx.x;
  const float sc = 0.08838834764831845f;
  float s = 0.f;
  for(int j=0;j<128;j++) s += wq[j*128+i]*wk[j*128+d];
  wct[d*128+i] = s*sc;
  if(i==0){
    float b=0.f;
    for(int j=0;j<128;j++) b += bq[j]*wk[j*128+d];
    bc[d] = b*sc;
  }
}

// ======================= small cross-attention (32 keys!) =======================
// out[q, col0+d] = bv[d] + ( sum_j exp(q2[q].m[j] - mx) * mv[j][d] ) / sum_j exp(...)
// block 256 = 128 queries x 2 dim-halves; market (32x128) + mv (32x128) staged in LDS.
__global__ __launch_bounds__(256) void attn_small(const float* q2, const float* mkt,
    const float* mv, const float* bv, float* outp, int ldc, int nq){
  __shared__ float ks[32][128];
  __shared__ float vs[32][128];
  int tid = threadIdx.x;
  for(int i=tid; i<N_KEYS*128; i+=256){
    ks[i>>7][i&127] = mkt[i];
    vs[i>>7][i&127] = mv[i];
  }
  __syncthreads();
  int q_loc = tid>>1;
  int dhalf = (tid&1)*64;
  int qg = blockIdx.x*128 + q_loc;
  int qr = qg < nq ? qg : nq-1;
  float4 qv[16];
  #pragma unroll
  for(int i=0;i<16;i++) qv[i] = *(const float4*)(q2 + (size_t)qr*128 + dhalf + i*4);
  float lg[N_KEYS];
  #pragma unroll
  for(int j=0;j<N_KEYS;j++){
    float l = 0.f;
    #pragma unroll
    for(int i=0;i<16;i++){
      float4 kv = *(const float4*)&ks[j][dhalf + i*4];
      l += qv[i].x*kv.x + qv[i].y*kv.y + qv[i].z*kv.z + qv[i].w*kv.w;
    }
    l += __shfl_xor(l, 1);   // combine the two 64-dim halves
    lg[j] = l;
  }
  float mx = -3.0e38f;
  #pragma unroll
  for(int j=0;j<N_KEYS;j++) mx = fmaxf(mx, lg[j]);
  float ssum = 0.f;
  #pragma unroll
  for(int j=0;j<N_KEYS;j++){ lg[j] = __expf(lg[j]-mx); ssum += lg[j]; }
  float inv = 1.f/ssum;
  float4 ov[16];
  #pragma unroll
  for(int i=0;i<16;i++) ov[i] = (float4){0.f,0.f,0.f,0.f};
  #pragma unroll
  for(int j=0;j<N_KEYS;j++){
    float p = lg[j];
    #pragma unroll
    for(int i=0;i<16;i++){
      float4 vv = *(const float4*)&vs[j][dhalf + i*4];
      ov[i].x += p*vv.x; ov[i].y += p*vv.y; ov[i].z += p*vv.z; ov[i].w += p*vv.w;
    }
  }
  if(qg < nq){
    #pragma unroll
    for(int i=0;i<16;i++){
      float4 bvv = *(const float4*)(bv + dhalf + i*4);
      float4 r;
      r.x = ov[i].x*inv + bvv.x;
      r.y = ov[i].y*inv + bvv.y;
      r.z = ov[i].z*inv + bvv.z;
      r.w = ov[i].w*inv + bvv.w;
      *(float4*)(outp + (size_t)qg*ldc + dhalf + i*4) = r;
    }
  }
}

__global__ void copy_h1(const float* h1, float* cat){
  int gid = blockIdx.x*256+threadIdx.x;
  int q = gid>>7, c = gid&127;
  if(q<N_NODES) cat[(size_t)q*512 + c] = h1[gid];
}

// ======================= host =======================
extern "C" void kernel_launch(void* const* d_in, const int* in_sizes, int n_in,
                              void* d_out, int out_size, void* d_ws, size_t ws_size,
                              hipStream_t stream) {
  const float* xts  = (const float*)d_in[0];
  const float* xgr  = (const float*)d_in[1];
  const float* ew   = (const float*)d_in[2];
  const int*   ei   = (const int*)d_in[3];
  const float* gwih = (const float*)d_in[4];
  const float* gwhh = (const float*)d_in[5];
  const float* gattn= (const float*)d_in[6];
  const float* g1aW = (const float*)d_in[7];
  const float* g1aAS= (const float*)d_in[8];
  const float* g1aAD= (const float*)d_in[9];
  const float* g1aAE= (const float*)d_in[10];
  const float* g1aLE= (const float*)d_in[11];
  const float* g1aB = (const float*)d_in[12];
  const float* g1bW = (const float*)d_in[13];
  const float* g1bAS= (const float*)d_in[14];
  const float* g1bAD= (const float*)d_in[15];
  const float* g1bAE= (const float*)d_in[16];
  const float* g1bLE= (const float*)d_in[17];
  const float* g1bB = (const float*)d_in[18];
  const float* mk1  = (const float*)d_in[19];   // (32,128)
  const float* mk2  = (const float*)d_in[20];   // (32,128)
  const float* caWq = (const float*)d_in[21];
  const float* caWk = (const float*)d_in[22];
  const float* caWv = (const float*)d_in[23];
  const float* caBq = (const float*)d_in[24];
  const float* caBv = (const float*)d_in[26];
  const float* saWv = (const float*)d_in[29];
  const float* saBv = (const float*)d_in[32];
  const float* f1W  = (const float*)d_in[33];
  const float* f1AS = (const float*)d_in[34];
  const float* f1AD = (const float*)d_in[35];
  const float* f1AE = (const float*)d_in[36];
  const float* f1LE = (const float*)d_in[37];
  const float* f1B  = (const float*)d_in[38];
  const float* f2W  = (const float*)d_in[39];
  const float* f2AS = (const float*)d_in[40];
  const float* f2AD = (const float*)d_in[41];
  const float* f2AE = (const float*)d_in[42];
  const float* f2LE = (const float*)d_in[43];
  const float* f2B  = (const float*)d_in[44];

  char* base = (char*)d_ws;
  char* p = base;
  auto alloc = [&](size_t bytes)->void*{
    void* r = (void*)p;
    p += (bytes + 255) & ~(size_t)255;
    return r;
  };
  float* h0   = (float*)alloc((size_t)N_NODES*128*4);
  float* h1b  = (float*)alloc((size_t)N_NODES*128*4);
  float* q2   = (float*)alloc((size_t)N_NODES*128*4);
  float* hG   = (float*)alloc((size_t)N_NODES*256*4);
  float* gb   = (float*)alloc((size_t)N_NODES*256*4);
  float* cat  = (float*)alloc((size_t)N_NODES*512*4);
  float* attb = (float*)alloc((size_t)N_NODES*512*4);
  float* mv   = (float*)alloc((size_t)N_KEYS*128*4);
  int*   deg  = (int*)  alloc((size_t)N_NODES*4);
  float* msum = (float*)alloc(256);
  float* Lb   = (float*)alloc((size_t)N_NODES*5*4);
  float* Lp   = (float*)alloc(40*10*4);
  float* msred= (float*)alloc(256);
  int*   rp   = (int*)  alloc((N_NODES+1)*4);
  int*   cur  = (int*)  alloc(N_NODES*4);
  int*   csr  = (int*)  alloc((size_t)(N_EDGES+N_NODES)*4);
  float* als  = (float*)alloc((size_t)N_NODES*2*4);
  float* ald  = (float*)alloc((size_t)N_NODES*2*4);
  float* ce   = (float*)alloc(256);
  float* wct  = (float*)alloc(128*128*4);
  float* bc   = (float*)alloc(512);
  size_t need = (size_t)(p - base);

  if(ws_size < need){
    kprobe<<<40,256,0,stream>>>((float*)d_out, -(float)ws_size, out_size);
    return;
  }

  // init
  kzero<<<2048,256,0,stream>>>(h0, (long)N_NODES*128);
  izero<<<64,256,0,stream>>>(deg, N_NODES);
  kzero<<<1,256,0,stream>>>(msum, 1);
  ksum_ew<<<(N_EDGES+255)/256,256,0,stream>>>(ew, msum, N_EDGES);

  // GRU (final h lands in h0 after 32 steps)
  for(int t=0;t<32;t++){
    const float* hin = (t&1) ? h1b : h0;
    float* hout = (t&1) ? h0 : h1b;
    gru_attn_logits<<<(N_NODES+255)/256,256,0,stream>>>(hin, gattn, Lb, Lp, N_NODES);
    gru_attn_reduce<<<1,64,0,stream>>>(Lp, msred, (N_NODES+255)/256);
    gru_step<<<N_NODES/16,256,0,stream>>>(hin, xts, Lb, msred, gwih, gwhh, hout, t);
  }

  // CSR (shared by all GATs)
  csr_deg<<<(N_EDGES+N_NODES+255)/256,256,0,stream>>>(ei, deg, N_EDGES, N_NODES);
  csr_scan<<<1,1024,0,stream>>>(deg, rp, cur, N_NODES);
  csr_fill<<<(N_EDGES+N_NODES+255)/256,256,0,stream>>>(ei, cur, csr, N_EDGES, N_NODES);

  // g1a: x_graph(10000,64) -> g (10000,256) relu
  gemm_abt<<<dim3(157,4),256,0,stream>>>(xgr,64, g1aW,64, nullptr, hG,256, N_NODES,256,64);
  gat_alsd<<<(N_NODES*2+255)/256,256,0,stream>>>(hG, g1aAS, g1aAD, g1aLE, g1aAE, als, ald, ce, N_NODES, 2, 128);
  gat_agg<<<N_NODES,256,0,stream>>>(hG, als, ald, ew, ei, rp, csr, ce, msum, g1aB, gb, 256, 0, 2, 128, N_EDGES, 1);
  // g1b: g -> x_gat (10000,128) into cat cols [128,256)
  gemm_abt<<<dim3(157,2),256,0,stream>>>(gb,256, g1bW,256, nullptr, hG,128, N_NODES,128,256);
  gat_alsd<<<(N_NODES+255)/256,256,0,stream>>>(hG, g1bAS, g1bAD, g1bLE, g1bAE, als, ald, ce, N_NODES, 1, 128);
  gat_agg<<<N_NODES,256,0,stream>>>(hG, als, ald, ew, ei, rp, csr, ce, msum, g1bB, cat, 512, 128, 1, 128, N_EDGES, 0);

  copy_h1<<<(N_NODES*128+255)/256,256,0,stream>>>(h0, cat);
  make_wc<<<128,128,0,stream>>>(caWq, caWk, caBq, wct, bc);

  // ---- attention 1: q from h1, market1 (32 keys) -> cat cols [256,384) ----
  lin_nt<<<(N_NODES*128+255)/256,256,0,stream>>>(h0,128, wct,128, bc, q2,128, N_NODES,128,128, 0);
  lin_nt<<<(N_KEYS*128+255)/256,256,0,stream>>>(mk1,128, caWv,128, nullptr, mv,128, N_KEYS,128,128, 0);
  attn_small<<<79,256,0,stream>>>(q2, mk1, mv, caBv, cat+256, 512, N_NODES);

  // ---- attention 2: q from x_gat (cat cols 128..255), market2 -> cat cols [384,512) ----
  lin_nt<<<(N_NODES*128+255)/256,256,0,stream>>>(cat+128,512, wct,128, bc, q2,128, N_NODES,128,128, 0);
  lin_nt<<<(N_KEYS*128+255)/256,256,0,stream>>>(mk2,128, caWv,128, nullptr, mv,128, N_KEYS,128,128, 0);
  attn_small<<<79,256,0,stream>>>(q2, mk2, mv, caBv, cat+384, 512, N_NODES);

  // self-attn over singleton == linear: att = cat @ saWv^T + saBv
  lin_nt<<<(N_NODES*512+255)/256,256,0,stream>>>(cat,512, saWv,512, saBv, attb,512, N_NODES,512,512, 0);

  // f1 GAT: att(512) -> y1 (64) relu
  lin_nt<<<(N_NODES*64+255)/256,256,0,stream>>>(attb,512, f1W,512, nullptr, hG,64, N_NODES,64,512, 0);
  gat_alsd<<<(N_NODES+255)/256,256,0,stream>>>(hG, f1AS, f1AD, f1LE, f1AE, als, ald, ce, N_NODES, 1, 64);
  gat_agg<<<N_NODES,256,0,stream>>>(hG, als, ald, ew, ei, rp, csr, ce, msum, f1B, gb, 64, 0, 1, 64, N_EDGES, 1);

  // f2 GAT: y1(64) -> out (1) + final relu, straight to d_out
  lin_nt<<<(N_NODES+255)/256,256,0,stream>>>(gb,64, f2W,64, nullptr, hG,1, N_NODES,1,64, 0);
  gat_alsd<<<(N_NODES+255)/256,256,0,stream>>>(hG, f2AS, f2AD, f2LE, f2AE, als, ald, ce, N_NODES, 1, 1);
  gat_agg<<<N_NODES,256,0,stream>>>(hG, als, ald, ew, ei, rp, csr, ce, msum, f2B, (float*)d_out, 1, 0, 1, 1, N_EDGES, 1);

  (void)in_sizes; (void)n_in; (void)out_size; (void)ws_size;
}

// Round 11
// 2231.992 us; speedup vs baseline: 5.5734x; 5.5734x over previous
//
#include <hip/hip_runtime.h>
#include <hip/hip_bf16.h>
#include <stdint.h>

#define N_NODES 10000
#define N_EDGES 320000
#define N_KEYS  32      // market1/market2 are (32,128) — K=32 in the reference!

// ======================= utility =======================
__global__ void kzero(float* p, long n){
  long i = (long)blockIdx.x*blockDim.x + threadIdx.x;
  long st = (long)gridDim.x*blockDim.x;
  for(; i<n; i+=st) p[i]=0.f;
}

__global__ void izero(int* p, long n){
  long i = (long)blockIdx.x*blockDim.x + threadIdx.x;
  long st = (long)gridDim.x*blockDim.x;
  for(; i<n; i+=st) p[i]=0;
}

__global__ void kprobe(float* out, float v, int n){
  int i = blockIdx.x*256 + threadIdx.x;
  if(i<n) out[i] = (i==0) ? v : 0.f;
}

__global__ void ksum_ew(const float* ew, float* out, int n){
  __shared__ float red[256];
  int gid = blockIdx.x*256 + threadIdx.x;
  red[threadIdx.x] = gid<n ? ew[gid] : 0.f;
  __syncthreads();
  for(int off=128; off>0; off>>=1){
    if(threadIdx.x<off) red[threadIdx.x]+=red[threadIdx.x+off];
    __syncthreads();
  }
  if(threadIdx.x==0) atomicAdd(out, red[0]);
}

// ======================= naive linear (small shapes only) =======================
__global__ void lin_nt(const float* A, int lda, const float* B, int ldb, const float* bias,
    float* C, int ldc, int M, int N, int K, int relu){
  int gid = blockIdx.x*256 + threadIdx.x;
  if(gid >= M*N) return;
  int m = gid / N, n = gid - m*N;
  const float* a = A + (size_t)m*lda;
  const float* b = B + (size_t)n*ldb;
  float s = bias ? bias[n] : 0.f;
  for(int k=0;k<K;k++) s += a[k]*b[k];
  if(relu) s = fmaxf(s, 0.f);
  C[(size_t)m*ldc + n] = s;
}

// ======================= GRU (validated r5/r9) =======================
__global__ __launch_bounds__(256) void gru_attn_logits(const float* h, const float* ga,
    float* L, float* part, int n){
  int row = blockIdx.x*256 + threadIdx.x;
  float acc[5] = {0,0,0,0,0};
  if(row < n){
    const float4* hr = (const float4*)(h + (size_t)row*128);
    for(int k4=0;k4<32;k4++){
      float4 v = hr[k4];
      #pragma unroll
      for(int c=0;c<5;c++){
        const float* g = ga + c*128 + k4*4;
        acc[c] += v.x*g[0]+v.y*g[1]+v.z*g[2]+v.w*g[3];
      }
    }
    #pragma unroll
    for(int c=0;c<5;c++) L[(size_t)row*5+c] = acc[c];
  }
  __shared__ float sm[256], ss[256];
  for(int c=0;c<5;c++){
    sm[threadIdx.x] = row<n ? acc[c] : -3.0e38f;
    ss[threadIdx.x] = row<n ? 1.f : 0.f;
    __syncthreads();
    for(int off=128; off>0; off>>=1){
      if(threadIdx.x < off){
        float m1=sm[threadIdx.x], m2=sm[threadIdx.x+off];
        float s1=ss[threadIdx.x], s2=ss[threadIdx.x+off];
        float M = fmaxf(m1,m2);
        sm[threadIdx.x]=M;
        ss[threadIdx.x]=s1*__expf(m1-M) + s2*__expf(m2-M);
      }
      __syncthreads();
    }
    if(threadIdx.x==0){ part[blockIdx.x*10 + c*2] = sm[0]; part[blockIdx.x*10 + c*2+1] = ss[0]; }
    __syncthreads();
  }
}

__global__ void gru_attn_reduce(const float* part, float* ms, int nblk){
  int c = threadIdx.x;
  if(c>=5) return;
  float M=-3.0e38f, S=0.f;
  for(int b=0;b<nblk;b++){
    float m2=part[b*10+c*2], s2=part[b*10+c*2+1];
    float Mn = fmaxf(M,m2);
    S = S*__expf(M-Mn) + s2*__expf(m2-Mn);
    M = Mn;
  }
  ms[c] = M; ms[5+c] = 1.f/S;
}

__global__ __launch_bounds__(256) void gru_step(const float* h, const float* xts, const float* L,
    const float* ms, const float* wih, const float* whh, float* hout, int t){
  __shared__ float hl[16][128];
  __shared__ float sg[16][256];
  __shared__ float xg[16][5];
  int n0 = blockIdx.x*16;
  int tid = threadIdx.x;
  const float4* src = (const float4*)(h + (size_t)n0*128);
  float4* dst4 = (float4*)&hl[0][0];
  for(int i=tid;i<512;i+=256) dst4[i] = src[i];
  if(tid < 80){
    int i = tid/5, f = tid%5;
    int node = n0+i;
    float xt = xts[(size_t)node*160 + t*5 + f];
    float aw = __expf(L[(size_t)node*5+f] - ms[f]) * ms[5+f];
    xg[i][f] = xt*aw;
  }
  __syncthreads();
  float wf[5];
  #pragma unroll
  for(int f=0;f<5;f++) wf[f] = wih[tid*5+f];
  float acc[16];
  #pragma unroll
  for(int i=0;i<16;i++) acc[i]=0.f;
  const float* wr = whh + (size_t)tid*128;
  for(int k4=0;k4<32;k4++){
    float4 wv = *(const float4*)(wr + k4*4);
    #pragma unroll
    for(int i=0;i<16;i++){
      float4 hv = *(const float4*)&hl[i][k4*4];
      acc[i] += wv.x*hv.x + wv.y*hv.y + wv.z*hv.z + wv.w*hv.w;
    }
  }
  #pragma unroll
  for(int i=0;i<16;i++){
    float g = acc[i];
    #pragma unroll
    for(int f=0;f<5;f++) g += xg[i][f]*wf[f];
    sg[i][tid] = 1.f/(1.f+__expf(-g));
  }
  __syncthreads();
  #pragma unroll
  for(int ii=0;ii<8;ii++){
    int e = tid + ii*256;
    int i = e>>7, col = e&127;
    float r = sg[i][col], u = sg[i][col+128], hv = hl[i][col];
    float nh = u*hv + (1.f-u)*tanhf(r*hv);
    hout[(size_t)(n0+i)*128 + col] = nh;
  }
}

// ======================= tiled fp32 GEMM (validated r5/r9) =======================
__global__ __launch_bounds__(256) void gemm_abt(const float* A, int lda, const float* B, int ldb,
    const float* bias, float* C, int ldc, int M, int N, int K){
  __shared__ float As[16][68];
  __shared__ float Bs[16][68];
  int m0 = blockIdx.x*64, n0 = blockIdx.y*64;
  int tid = threadIdx.x;
  int tx = tid & 15, ty = tid >> 4;
  float acc[4][4] = {};
  for(int k0=0;k0<K;k0+=16){
    int mm = tid & 63, kc = tid >> 6;
    float4 v = {0,0,0,0};
    if(m0+mm < M) v = *(const float4*)(A + (size_t)(m0+mm)*lda + k0 + kc*4);
    As[kc*4+0][mm]=v.x; As[kc*4+1][mm]=v.y; As[kc*4+2][mm]=v.z; As[kc*4+3][mm]=v.w;
    float4 w = {0,0,0,0};
    if(n0+mm < N) w = *(const float4*)(B + (size_t)(n0+mm)*ldb + k0 + kc*4);
    Bs[kc*4+0][mm]=w.x; Bs[kc*4+1][mm]=w.y; Bs[kc*4+2][mm]=w.z; Bs[kc*4+3][mm]=w.w;
    __syncthreads();
    #pragma unroll
    for(int kk=0;kk<16;kk++){
      float4 a = *(const float4*)&As[kk][ty*4];
      float4 b = *(const float4*)&Bs[kk][tx*4];
      acc[0][0]+=a.x*b.x; acc[0][1]+=a.x*b.y; acc[0][2]+=a.x*b.z; acc[0][3]+=a.x*b.w;
      acc[1][0]+=a.y*b.x; acc[1][1]+=a.y*b.y; acc[1][2]+=a.y*b.z; acc[1][3]+=a.y*b.w;
      acc[2][0]+=a.z*b.x; acc[2][1]+=a.z*b.y; acc[2][2]+=a.z*b.z; acc[2][3]+=a.z*b.w;
      acc[3][0]+=a.w*b.x; acc[3][1]+=a.w*b.y; acc[3][2]+=a.w*b.z; acc[3][3]+=a.w*b.w;
    }
    __syncthreads();
  }
  #pragma unroll
  for(int i=0;i<4;i++){
    #pragma unroll
    for(int j=0;j<4;j++){
      int m = m0+ty*4+i, n = n0+tx*4+j;
      if(m<M && n<N){
        float vv = acc[i][j] + (bias ? bias[n] : 0.f);
        C[(size_t)m*ldc + n] = vv;
      }
    }
  }
}

// ======================= GAT (validated r5/r9) =======================
__global__ void gat_alsd(const float* h, const float* asrc, const float* adst,
    const float* line, const float* aedge, float* al_s, float* al_d, float* ce,
    int n, int heads, int outd){
  int id = blockIdx.x*256 + threadIdx.x;
  if(id < heads){
    float c=0;
    for(int o=0;o<outd;o++) c += line[id*outd+o]*aedge[id*outd+o];
    ce[id]=c;
  }
  if(id >= n*heads) return;
  int node = id/heads, hh = id%heads;
  const float* hr = h + (size_t)node*heads*outd + hh*outd;
  const float* as = asrc + hh*outd;
  const float* ad = adst + hh*outd;
  float s=0.f, d=0.f;
  for(int o=0;o<outd;o++){ float v=hr[o]; s+=v*as[o]; d+=v*ad[o]; }
  al_s[id]=s; al_d[id]=d;
}

__global__ void csr_deg(const int* ei, int* deg, int E, int n){
  int e = blockIdx.x*256+threadIdx.x;
  if(e>=E+n) return;
  int d = e<E ? ei[E+e] : e-E;
  atomicAdd(&deg[d], 1);
}

__global__ void csr_scan(const int* deg, int* rp, int* cur, int n){
  __shared__ int s[1024];
  int carry = 0;
  if(threadIdx.x==0) rp[0]=0;
  for(int c0=0;c0<n;c0+=1024){
    int i = c0+(int)threadIdx.x;
    int v = i<n ? deg[i] : 0;
    s[threadIdx.x]=v;
    __syncthreads();
    for(int off=1; off<1024; off<<=1){
      int t = threadIdx.x>=(unsigned)off ? s[threadIdx.x-off] : 0;
      __syncthreads();
      s[threadIdx.x]+=t;
      __syncthreads();
    }
    if(i<n){ rp[i+1] = carry + s[threadIdx.x]; cur[i] = carry + s[threadIdx.x] - v; }
    carry += s[1023];
    __syncthreads();
  }
}

__global__ void csr_fill(const int* ei, int* cur, int* csr, int E, int n){
  int e = blockIdx.x*256+threadIdx.x;
  if(e>=E+n) return;
  int d = e<E ? ei[E+e] : e-E;
  int slot = atomicAdd(&cur[d], 1);
  csr[slot] = e;
}

__global__ __launch_bounds__(256) void gat_agg(const float* h, const float* al_s, const float* al_d,
    const float* ew, const int* ei, const int* rp, const int* csr, const float* ce, const float* msum,
    const float* bias, float* out, int ldc, int col0, int heads, int outd, int E, int relu){
  int n = blockIdx.x;
  int tid = threadIdx.x;
  int p0 = rp[n], cnt = rp[n+1]-p0;
  float meanw = msum[0] * (1.f/(float)N_EDGES);
  __shared__ float red[256];
  __shared__ float sw[2][256];
  __shared__ int ssrc[256];
  __shared__ float smx[2], sden[2];
  float ald0 = al_d[(size_t)n*heads+0];
  float ald1 = heads>1 ? al_d[(size_t)n*heads+1] : 0.f;
  float ce0 = ce[0], ce1 = heads>1 ? ce[1] : 0.f;
  float mx0=-3.0e38f, mx1=-3.0e38f;
  for(int i=tid;i<cnt;i+=256){
    int e = csr[p0+i];
    int srcn = e<E ? ei[e] : e-E;
    float ea = e<E ? ew[e] : meanw;
    float a0 = al_s[(size_t)srcn*heads+0] + ald0 + ea*ce0;
    a0 = a0>=0.f ? a0 : 0.2f*a0;
    mx0 = fmaxf(mx0,a0);
    if(heads>1){
      float a1 = al_s[(size_t)srcn*heads+1] + ald1 + ea*ce1;
      a1 = a1>=0.f ? a1 : 0.2f*a1;
      mx1 = fmaxf(mx1,a1);
    }
  }
  red[tid]=mx0; __syncthreads();
  for(int off=128;off>0;off>>=1){ if(tid<off) red[tid]=fmaxf(red[tid],red[tid+off]); __syncthreads(); }
  if(tid==0) smx[0]=red[0];
  __syncthreads();
  if(heads>1){
    red[tid]=mx1; __syncthreads();
    for(int off=128;off>0;off>>=1){ if(tid<off) red[tid]=fmaxf(red[tid],red[tid+off]); __syncthreads(); }
    if(tid==0) smx[1]=red[0];
    __syncthreads();
  }
  float den0=0.f, den1=0.f, acc=0.f;
  int myh = outd>0 ? tid/outd : 0;
  int ok = tid < heads*outd;
  if(myh>1) myh=1;
  for(int c0=0;c0<cnt;c0+=256){
    int ccnt = min(256, cnt-c0);
    __syncthreads();
    if(tid < ccnt){
      int e = csr[p0+c0+tid];
      int srcn = e<E ? ei[e] : e-E;
      float ea = e<E ? ew[e] : meanw;
      float a0 = al_s[(size_t)srcn*heads+0] + ald0 + ea*ce0;
      a0 = a0>=0.f ? a0 : 0.2f*a0;
      float w0 = __expf(a0 - smx[0]);
      sw[0][tid]=w0; den0 += w0;
      if(heads>1){
        float a1 = al_s[(size_t)srcn*heads+1] + ald1 + ea*ce1;
        a1 = a1>=0.f ? a1 : 0.2f*a1;
        float w1 = __expf(a1 - smx[1]);
        sw[1][tid]=w1; den1 += w1;
      }
      ssrc[tid]=srcn;
    }
    __syncthreads();
    if(ok){
      for(int j=0;j<ccnt;j++){
        acc += sw[myh][j] * h[(size_t)ssrc[j]*heads*outd + tid];
      }
    }
  }
  red[tid]=den0; __syncthreads();
  for(int off=128;off>0;off>>=1){ if(tid<off) red[tid]+=red[tid+off]; __syncthreads(); }
  if(tid==0) sden[0]=red[0];
  __syncthreads();
  if(heads>1){
    red[tid]=den1; __syncthreads();
    for(int off=128;off>0;off>>=1){ if(tid<off) red[tid]+=red[tid+off]; __syncthreads(); }
    if(tid==0) sden[1]=red[0];
    __syncthreads();
  }
  if(ok){
    float v = acc/(sden[myh]+1e-16f) + bias[tid];
    if(relu) v = fmaxf(v,0.f);
    out[(size_t)n*ldc + col0 + tid] = v;
  }
}

// ======================= attention prep (validated r5/r9) =======================
__global__ void make_wc(const float* wq, const float* wk, const float* bq, float* wct, float* bc){
  int d = blockIdx.x, i = threadIdx.x;
  const float sc = 0.08838834764831845f;
  float s = 0.f;
  for(int j=0;j<128;j++) s += wq[j*128+i]*wk[j*128+d];
  wct[d*128+i] = s*sc;
  if(i==0){
    float b=0.f;
    for(int j=0;j<128;j++) b += bq[j]*wk[j*128+d];
    bc[d] = b*sc;
  }
}

// ======================= small cross-attention (32 keys, validated r9) =======================
__global__ __launch_bounds__(256) void attn_small(const float* q2, const float* mkt,
    const float* mv, const float* bv, float* outp, int ldc, int nq){
  __shared__ float ks[32][128];
  __shared__ float vs[32][128];
  int tid = threadIdx.x;
  for(int i=tid; i<N_KEYS*128; i+=256){
    ks[i>>7][i&127] = mkt[i];
    vs[i>>7][i&127] = mv[i];
  }
  __syncthreads();
  int q_loc = tid>>1;
  int dhalf = (tid&1)*64;
  int qg = blockIdx.x*128 + q_loc;
  int qr = qg < nq ? qg : nq-1;
  float4 qv[16];
  #pragma unroll
  for(int i=0;i<16;i++) qv[i] = *(const float4*)(q2 + (size_t)qr*128 + dhalf + i*4);
  float lg[N_KEYS];
  #pragma unroll
  for(int j=0;j<N_KEYS;j++){
    float l = 0.f;
    #pragma unroll
    for(int i=0;i<16;i++){
      float4 kv = *(const float4*)&ks[j][dhalf + i*4];
      l += qv[i].x*kv.x + qv[i].y*kv.y + qv[i].z*kv.z + qv[i].w*kv.w;
    }
    l += __shfl_xor(l, 1);
    lg[j] = l;
  }
  float mx = -3.0e38f;
  #pragma unroll
  for(int j=0;j<N_KEYS;j++) mx = fmaxf(mx, lg[j]);
  float ssum = 0.f;
  #pragma unroll
  for(int j=0;j<N_KEYS;j++){ lg[j] = __expf(lg[j]-mx); ssum += lg[j]; }
  float inv = 1.f/ssum;
  float4 ov[16];
  #pragma unroll
  for(int i=0;i<16;i++) ov[i] = (float4){0.f,0.f,0.f,0.f};
  #pragma unroll
  for(int j=0;j<N_KEYS;j++){
    float p = lg[j];
    #pragma unroll
    for(int i=0;i<16;i++){
      float4 vv = *(const float4*)&vs[j][dhalf + i*4];
      ov[i].x += p*vv.x; ov[i].y += p*vv.y; ov[i].z += p*vv.z; ov[i].w += p*vv.w;
    }
  }
  if(qg < nq){
    #pragma unroll
    for(int i=0;i<16;i++){
      float4 bvv = *(const float4*)(bv + dhalf + i*4);
      float4 r;
      r.x = ov[i].x*inv + bvv.x;
      r.y = ov[i].y*inv + bvv.y;
      r.z = ov[i].z*inv + bvv.z;
      r.w = ov[i].w*inv + bvv.w;
      *(float4*)(outp + (size_t)qg*ldc + dhalf + i*4) = r;
    }
  }
}

__global__ void copy_h1(const float* h1, float* cat){
  int gid = blockIdx.x*256+threadIdx.x;
  int q = gid>>7, c = gid&127;
  if(q<N_NODES) cat[(size_t)q*512 + c] = h1[gid];
}

// ======================= host =======================
extern "C" void kernel_launch(void* const* d_in, const int* in_sizes, int n_in,
                              void* d_out, int out_size, void* d_ws, size_t ws_size,
                              hipStream_t stream) {
  const float* xts  = (const float*)d_in[0];
  const float* xgr  = (const float*)d_in[1];
  const float* ew   = (const float*)d_in[2];
  const int*   ei   = (const int*)d_in[3];
  const float* gwih = (const float*)d_in[4];
  const float* gwhh = (const float*)d_in[5];
  const float* gattn= (const float*)d_in[6];
  const float* g1aW = (const float*)d_in[7];
  const float* g1aAS= (const float*)d_in[8];
  const float* g1aAD= (const float*)d_in[9];
  const float* g1aAE= (const float*)d_in[10];
  const float* g1aLE= (const float*)d_in[11];
  const float* g1aB = (const float*)d_in[12];
  const float* g1bW = (const float*)d_in[13];
  const float* g1bAS= (const float*)d_in[14];
  const float* g1bAD= (const float*)d_in[15];
  const float* g1bAE= (const float*)d_in[16];
  const float* g1bLE= (const float*)d_in[17];
  const float* g1bB = (const float*)d_in[18];
  const float* mk1  = (const float*)d_in[19];   // (32,128)
  const float* mk2  = (const float*)d_in[20];   // (32,128)
  const float* caWq = (const float*)d_in[21];
  const float* caWk = (const float*)d_in[22];
  const float* caWv = (const float*)d_in[23];
  const float* caBq = (const float*)d_in[24];
  const float* caBv = (const float*)d_in[26];
  const float* saWv = (const float*)d_in[29];
  const float* saBv = (const float*)d_in[32];
  const float* f1W  = (const float*)d_in[33];
  const float* f1AS = (const float*)d_in[34];
  const float* f1AD = (const float*)d_in[35];
  const float* f1AE = (const float*)d_in[36];
  const float* f1LE = (const float*)d_in[37];
  const float* f1B  = (const float*)d_in[38];
  const float* f2W  = (const float*)d_in[39];
  const float* f2AS = (const float*)d_in[40];
  const float* f2AD = (const float*)d_in[41];
  const float* f2AE = (const float*)d_in[42];
  const float* f2LE = (const float*)d_in[43];
  const float* f2B  = (const float*)d_in[44];

  char* base = (char*)d_ws;
  char* p = base;
  auto alloc = [&](size_t bytes)->void*{
    void* r = (void*)p;
    p += (bytes + 255) & ~(size_t)255;
    return r;
  };
  float* h0   = (float*)alloc((size_t)N_NODES*128*4);
  float* h1b  = (float*)alloc((size_t)N_NODES*128*4);
  float* q2   = (float*)alloc((size_t)N_NODES*128*4);
  float* hG   = (float*)alloc((size_t)N_NODES*256*4);
  float* gb   = (float*)alloc((size_t)N_NODES*256*4);
  float* cat  = (float*)alloc((size_t)N_NODES*512*4);
  float* attb = (float*)alloc((size_t)N_NODES*512*4);
  float* mv   = (float*)alloc((size_t)N_KEYS*128*4);
  int*   deg  = (int*)  alloc((size_t)N_NODES*4);
  float* msum = (float*)alloc(256);
  float* Lb   = (float*)alloc((size_t)N_NODES*5*4);
  float* Lp   = (float*)alloc(40*10*4);
  float* msred= (float*)alloc(256);
  int*   rp   = (int*)  alloc((N_NODES+1)*4);
  int*   cur  = (int*)  alloc(N_NODES*4);
  int*   csr  = (int*)  alloc((size_t)(N_EDGES+N_NODES)*4);
  float* als  = (float*)alloc((size_t)N_NODES*2*4);
  float* ald  = (float*)alloc((size_t)N_NODES*2*4);
  float* ce   = (float*)alloc(256);
  float* wct  = (float*)alloc(128*128*4);
  float* bc   = (float*)alloc(512);
  size_t need = (size_t)(p - base);

  if(ws_size < need){
    kprobe<<<40,256,0,stream>>>((float*)d_out, -(float)ws_size, out_size);
    return;
  }

  // init
  kzero<<<2048,256,0,stream>>>(h0, (long)N_NODES*128);
  izero<<<64,256,0,stream>>>(deg, N_NODES);
  kzero<<<1,256,0,stream>>>(msum, 1);
  ksum_ew<<<(N_EDGES+255)/256,256,0,stream>>>(ew, msum, N_EDGES);

  // GRU (final h lands in h0 after 32 steps)
  for(int t=0;t<32;t++){
    const float* hin = (t&1) ? h1b : h0;
    float* hout = (t&1) ? h0 : h1b;
    gru_attn_logits<<<(N_NODES+255)/256,256,0,stream>>>(hin, gattn, Lb, Lp, N_NODES);
    gru_attn_reduce<<<1,64,0,stream>>>(Lp, msred, (N_NODES+255)/256);
    gru_step<<<N_NODES/16,256,0,stream>>>(hin, xts, Lb, msred, gwih, gwhh, hout, t);
  }

  // CSR (shared by all GATs)
  csr_deg<<<(N_EDGES+N_NODES+255)/256,256,0,stream>>>(ei, deg, N_EDGES, N_NODES);
  csr_scan<<<1,1024,0,stream>>>(deg, rp, cur, N_NODES);
  csr_fill<<<(N_EDGES+N_NODES+255)/256,256,0,stream>>>(ei, cur, csr, N_EDGES, N_NODES);

  // g1a: x_graph(10000,64) -> g (10000,256) relu
  gemm_abt<<<dim3(157,4),256,0,stream>>>(xgr,64, g1aW,64, nullptr, hG,256, N_NODES,256,64);
  gat_alsd<<<(N_NODES*2+255)/256,256,0,stream>>>(hG, g1aAS, g1aAD, g1aLE, g1aAE, als, ald, ce, N_NODES, 2, 128);
  gat_agg<<<N_NODES,256,0,stream>>>(hG, als, ald, ew, ei, rp, csr, ce, msum, g1aB, gb, 256, 0, 2, 128, N_EDGES, 1);
  // g1b: g -> x_gat (10000,128) into cat cols [128,256)
  gemm_abt<<<dim3(157,2),256,0,stream>>>(gb,256, g1bW,256, nullptr, hG,128, N_NODES,128,256);
  gat_alsd<<<(N_NODES+255)/256,256,0,stream>>>(hG, g1bAS, g1bAD, g1bLE, g1bAE, als, ald, ce, N_NODES, 1, 128);
  gat_agg<<<N_NODES,256,0,stream>>>(hG, als, ald, ew, ei, rp, csr, ce, msum, g1bB, cat, 512, 128, 1, 128, N_EDGES, 0);

  copy_h1<<<(N_NODES*128+255)/256,256,0,stream>>>(h0, cat);
  make_wc<<<128,128,0,stream>>>(caWq, caWk, caBq, wct, bc);

  // ---- attention 1: q from h1, market1 (32 keys) -> cat cols [256,384) ----
  gemm_abt<<<dim3(157,2),256,0,stream>>>(h0,128, wct,128, bc, q2,128, N_NODES,128,128);
  lin_nt<<<(N_KEYS*128+255)/256,256,0,stream>>>(mk1,128, caWv,128, nullptr, mv,128, N_KEYS,128,128, 0);
  attn_small<<<79,256,0,stream>>>(q2, mk1, mv, caBv, cat+256, 512, N_NODES);

  // ---- attention 2: q from x_gat (cat cols 128..255), market2 -> cat cols [384,512) ----
  gemm_abt<<<dim3(157,2),256,0,stream>>>(cat+128,512, wct,128, bc, q2,128, N_NODES,128,128);
  lin_nt<<<(N_KEYS*128+255)/256,256,0,stream>>>(mk2,128, caWv,128, nullptr, mv,128, N_KEYS,128,128, 0);
  attn_small<<<79,256,0,stream>>>(q2, mk2, mv, caBv, cat+384, 512, N_NODES);

  // self-attn over singleton == linear: att = cat @ saWv^T + saBv  [was 9ms naive -> tiled]
  gemm_abt<<<dim3(157,8),256,0,stream>>>(cat,512, saWv,512, saBv, attb,512, N_NODES,512,512);

  // f1 GAT: att(512) -> y1 (64)
  gemm_abt<<<dim3(157,1),256,0,stream>>>(attb,512, f1W,512, nullptr, hG,64, N_NODES,64,512);
  gat_alsd<<<(N_NODES+255)/256,256,0,stream>>>(hG, f1AS, f1AD, f1LE, f1AE, als, ald, ce, N_NODES, 1, 64);
  gat_agg<<<N_NODES,256,0,stream>>>(hG, als, ald, ew, ei, rp, csr, ce, msum, f1B, gb, 64, 0, 1, 64, N_EDGES, 1);

  // f2 GAT: y1(64) -> out (1) + final relu, straight to d_out
  lin_nt<<<(N_NODES+255)/256,256,0,stream>>>(gb,64, f2W,64, nullptr, hG,1, N_NODES,1,64, 0);
  gat_alsd<<<(N_NODES+255)/256,256,0,stream>>>(hG, f2AS, f2AD, f2LE, f2AE, als, ald, ce, N_NODES, 1, 1);
  gat_agg<<<N_NODES,256,0,stream>>>(hG, als, ald, ew, ei, rp, csr, ce, msum, f2B, (float*)d_out, 1, 0, 1, 1, N_EDGES, 1);

  (void)in_sizes; (void)n_in; (void)out_size; (void)ws_size;
}